// Round 4
// baseline (440.642 us; speedup 1.0000x reference)
//
#include <hip/hip_runtime.h>
#include <hip/hip_bf16.h>

#define NN 16384
#define DD 256
#define BM 128
#define BN 128
#define BK 64
#define NKS (DD / BK)
#define THREADS 256
#define SHIFT_C 64.0f
#define LOG2E 1.4426950408889634f

typedef __attribute__((ext_vector_type(4))) float f32x4;
typedef __attribute__((ext_vector_type(8))) short bf16x8;

#if __has_builtin(__builtin_amdgcn_exp2f)
#define EXP2F(x) __builtin_amdgcn_exp2f(x)
#else
#define EXP2F(x) exp2f(x)
#endif

__device__ __forceinline__ unsigned pkbf(float a, float b) {
  float2 t; t.x = a; t.y = b;
  __hip_bfloat162 h = __float22bfloat162_rn(t);
  union { __hip_bfloat162 h; unsigned u; } cv;
  cv.h = h;
  return cv.u;
}

// ---------------- pre-convert f32 -> bf16 ----------------
__global__ __launch_bounds__(256) void cvt_kernel(
    const float* __restrict__ X, const float* __restrict__ Y,
    unsigned short* __restrict__ Xb, unsigned short* __restrict__ Yb) {
  const int groups_per_arr = NN * DD / 8;
  int g = blockIdx.x * 256 + threadIdx.x;
  const float* src;
  unsigned short* dst;
  if (g < groups_per_arr) { src = X; dst = Xb; }
  else { src = Y; dst = Yb; g -= groups_per_arr; }
  float4 a = ((const float4*)src)[(size_t)g * 2];
  float4 b = ((const float4*)src)[(size_t)g * 2 + 1];
  uint4 p = { pkbf(a.x, a.y), pkbf(a.z, a.w), pkbf(b.x, b.y), pkbf(b.z, b.w) };
  ((uint4*)dst)[g] = p;
}

// ---------------- main fused GEMM + softmax-stats ----------------
// Hybrid operand routing: A staged via double-buffered LDS (global_load_lds,
// source-pre-swizzled per rule #21); B fragments loaded DIRECTLY from L2 into
// registers (row-major Y, 16B contiguous per fragment) — halves LDS-pipe
// traffic. One barrier per K-step; stage/loads for ks+1 issued BEFORE
// compute(ks) so the vmcnt(0)-at-barrier drain lands after compute (T3 min).
__global__ __launch_bounds__(THREADS) void clip_gemm(
    const unsigned short* __restrict__ Xb, const unsigned short* __restrict__ Yb,
    float* __restrict__ rowsum, float* __restrict__ colsum,
    float* __restrict__ diagsum) {
  __shared__ __align__(16) unsigned char smA[2 * BM * BK * 2];  // 2 x 16 KB

  const int tid = threadIdx.x;
  const int bid = blockIdx.x;
  // 2-level XCD-aware swizzle: each XCD owns brows [16k,16k+16); within XCD,
  // 16x16-tile supertiles so X-slice (2MB) + Y-slice (2MB) are L2-resident.
  const int xcd = bid & 7;
  const int t = bid >> 3;
  const int st = t >> 8;
  const int idx = t & 255;
  const int brow = xcd * 16 + (idx >> 4);
  const int bcol = st * 16 + (idx & 15);

  const unsigned short* xb = Xb + (size_t)brow * BM * DD;
  const unsigned short* yb = Yb + (size_t)bcol * BN * DD;

  const int wid = tid >> 6, lane = tid & 63;
  const int wm = wid >> 1, wn = wid & 1;
  const int lm = lane & 15, lk = lane >> 4;

  const int srow0 = wid * 8 + (lane >> 3);
  const int skoff = (((lane & 7) ^ (lane >> 3)) << 3);  // inverse swizzle on source
  const int sldso = wid * 1024 + lane * 16;             // linear LDS dest

  // per-lane B base: row = bcol*128 + wn*64 + n*16 + lm, k-slot = lk*8
  const unsigned short* ybase = yb + (size_t)(wn * 64 + lm) * DD + lk * 8;

  f32x4 acc[4][4] = {};
  bf16x8 bfr[2][8];  // [buf][n*2+kk] — all indices compile-time (full unroll)

#define STAGE_A(ks, buf)                                                       \
  {                                                                            \
    _Pragma("unroll")                                                          \
    for (int i = 0; i < 4; ++i) {                                              \
      const int row = i * 32 + srow0;                                          \
      __builtin_amdgcn_global_load_lds(                                        \
          (const __attribute__((address_space(1))) unsigned*)(xb + (size_t)row * DD + (ks) * BK + skoff), \
          (__attribute__((address_space(3))) unsigned*)(smA + (buf) * 16384 + i * 4096 + sldso), \
          16, 0, 0);                                                           \
    }                                                                          \
  }

#define LOADB(ks, buf)                                                         \
  {                                                                            \
    _Pragma("unroll")                                                          \
    for (int n = 0; n < 4; ++n)                                                \
      _Pragma("unroll")                                                        \
      for (int kk = 0; kk < 2; ++kk)                                           \
        bfr[buf][n * 2 + kk] =                                                 \
            *(const bf16x8*)(ybase + n * 16 * DD + (ks) * BK + kk * 32);       \
  }

  // prologue
  STAGE_A(0, 0);
  LOADB(0, 0);
  __syncthreads();  // vmcnt(0): A(0) in LDS, bfr[0] ready

  const int rxor = (lm & 7) << 4;
#pragma unroll
  for (int ks = 0; ks < NKS; ++ks) {
    const int cur = ks & 1;
    if (ks < NKS - 1) {
      STAGE_A(ks + 1, cur ^ 1);   // issue early: drain happens at barrier below
      LOADB(ks + 1, cur ^ 1);
    }
#pragma unroll
    for (int kk = 0; kk < 2; ++kk) {
      const int kboff = (kk * 64 + lk * 16) ^ rxor;
      bf16x8 a[4];
#pragma unroll
      for (int m = 0; m < 4; ++m)
        a[m] = *(const bf16x8*)(smA + cur * 16384 + (wm * 64 + m * 16 + lm) * (BK * 2) + kboff);
#pragma unroll
      for (int m = 0; m < 4; ++m)
#pragma unroll
        for (int n = 0; n < 4; ++n)
          acc[m][n] = __builtin_amdgcn_mfma_f32_16x16x32_bf16(a[m], bfr[cur][n * 2 + kk], acc[m][n], 0, 0, 0);
    }
    if (ks < NKS - 1) __syncthreads();  // single barrier/K-step; drains stage
  }
#undef STAGE_A
#undef LOADB

  // ---- fused softmax-statistics epilogue ----
  float rowacc[4][4];
  float colacc[4];
#pragma unroll
  for (int m = 0; m < 4; ++m)
#pragma unroll
    for (int r = 0; r < 4; ++r) rowacc[m][r] = 0.f;
#pragma unroll
  for (int n = 0; n < 4; ++n) colacc[n] = 0.f;

  const float negC = -(SHIFT_C * LOG2E);
#pragma unroll
  for (int m = 0; m < 4; ++m)
#pragma unroll
    for (int n = 0; n < 4; ++n)
#pragma unroll
      for (int r = 0; r < 4; ++r) {
        float e = EXP2F(__builtin_fmaf(acc[m][n][r], LOG2E, negC));
        rowacc[m][r] += e;
        colacc[n] += e;
      }

  if (brow == bcol && wm == wn) {
    float dsum = 0.f;
#pragma unroll
    for (int m = 0; m < 4; ++m)
#pragma unroll
      for (int n = 0; n < 4; ++n)
#pragma unroll
        for (int r = 0; r < 4; ++r) {
          const int rr = m * 16 + lk * 4 + r;
          const int cc = n * 16 + lm;
          if (rr == cc) dsum += acc[m][n][r];
        }
    dsum += __shfl_xor(dsum, 1);
    dsum += __shfl_xor(dsum, 2);
    dsum += __shfl_xor(dsum, 4);
    dsum += __shfl_xor(dsum, 8);
    dsum += __shfl_xor(dsum, 16);
    dsum += __shfl_xor(dsum, 32);
    if (lane == 0) atomicAdd(diagsum, dsum);
  }

#pragma unroll
  for (int m = 0; m < 4; ++m)
#pragma unroll
    for (int r = 0; r < 4; ++r) {
      float v = rowacc[m][r];
      v += __shfl_xor(v, 1);
      v += __shfl_xor(v, 2);
      v += __shfl_xor(v, 4);
      v += __shfl_xor(v, 8);
      if (lm == 0)
        atomicAdd(&rowsum[brow * BM + wm * 64 + m * 16 + lk * 4 + r], v);
    }
#pragma unroll
  for (int n = 0; n < 4; ++n) {
    float v = colacc[n];
    v += __shfl_xor(v, 16);
    v += __shfl_xor(v, 32);
    if (lk == 0)
      atomicAdd(&colsum[bcol * BN + wn * 64 + n * 16 + lm], v);
  }
}

// ---------------- fallback (reg-staging, no ws bf16 buffers) ----------------
__global__ __launch_bounds__(THREADS) void clip_main_fb(
    const float* __restrict__ X, const float* __restrict__ Y,
    float* __restrict__ rowsum, float* __restrict__ colsum,
    float* __restrict__ diagsum) {
  __shared__ __align__(16) unsigned char smem[2 * BM * BK * 2];
  unsigned char* smA = smem;
  unsigned char* smB = smem + BM * BK * 2;

  const int tid = threadIdx.x;
  const int bid = blockIdx.x;
  const int swz = (bid & 7) * 2048 + (bid >> 3);
  const int brow = swz >> 7;
  const int bcol = swz & 127;

  const float* xb = X + (size_t)brow * BM * DD;
  const float* yb = Y + (size_t)bcol * BN * DD;

  const int wid = tid >> 6, lane = tid & 63;
  const int wm = wid >> 1, wn = wid & 1;
  const int lm = lane & 15, lk = lane >> 4;

  f32x4 acc[4][4] = {};

  for (int ks = 0; ks < NKS; ++ks) {
    const int kbase = ks * BK;
    if (ks) __syncthreads();
#pragma unroll
    for (int i = 0; i < 4; ++i) {
      const int c = tid + i * THREADS;
      const int row = c >> 3, slot = c & 7;
      const int boff = row * (BK * 2) + ((slot << 4) ^ ((row & 7) << 4));
      const float* ga = xb + row * DD + kbase + (slot << 3);
      float4 a0 = *(const float4*)ga;
      float4 a1 = *(const float4*)(ga + 4);
      uint4 pa = { pkbf(a0.x, a0.y), pkbf(a0.z, a0.w),
                   pkbf(a1.x, a1.y), pkbf(a1.z, a1.w) };
      *(uint4*)(smA + boff) = pa;
      const float* gb = yb + row * DD + kbase + (slot << 3);
      float4 b0 = *(const float4*)gb;
      float4 b1 = *(const float4*)(gb + 4);
      uint4 pb = { pkbf(b0.x, b0.y), pkbf(b0.z, b0.w),
                   pkbf(b1.x, b1.y), pkbf(b1.z, b1.w) };
      *(uint4*)(smB + boff) = pb;
    }
    __syncthreads();

#pragma unroll
    for (int kk = 0; kk < 2; ++kk) {
      const int kboff = kk * 64 + lk * 16;
      bf16x8 a[4], b[4];
#pragma unroll
      for (int m = 0; m < 4; ++m) {
        const int row = wm * 64 + m * 16 + lm;
        a[m] = *(const bf16x8*)(smA + row * (BK * 2) + (kboff ^ ((row & 7) << 4)));
      }
#pragma unroll
      for (int n = 0; n < 4; ++n) {
        const int row = wn * 64 + n * 16 + lm;
        b[n] = *(const bf16x8*)(smB + row * (BK * 2) + (kboff ^ ((row & 7) << 4)));
      }
#pragma unroll
      for (int m = 0; m < 4; ++m)
#pragma unroll
        for (int n = 0; n < 4; ++n)
          acc[m][n] = __builtin_amdgcn_mfma_f32_16x16x32_bf16(a[m], b[n], acc[m][n], 0, 0, 0);
    }
  }

  float rowacc[4][4];
  float colacc[4];
#pragma unroll
  for (int m = 0; m < 4; ++m)
#pragma unroll
    for (int r = 0; r < 4; ++r) rowacc[m][r] = 0.f;
#pragma unroll
  for (int n = 0; n < 4; ++n) colacc[n] = 0.f;

  const float negC = -(SHIFT_C * LOG2E);
#pragma unroll
  for (int m = 0; m < 4; ++m)
#pragma unroll
    for (int n = 0; n < 4; ++n)
#pragma unroll
      for (int r = 0; r < 4; ++r) {
        float e = EXP2F(__builtin_fmaf(acc[m][n][r], LOG2E, negC));
        rowacc[m][r] += e;
        colacc[n] += e;
      }

  if (brow == bcol && wm == wn) {
    float dsum = 0.f;
#pragma unroll
    for (int m = 0; m < 4; ++m)
#pragma unroll
      for (int n = 0; n < 4; ++n)
#pragma unroll
        for (int r = 0; r < 4; ++r) {
          const int rr = m * 16 + lk * 4 + r;
          const int cc = n * 16 + lm;
          if (rr == cc) dsum += acc[m][n][r];
        }
    dsum += __shfl_xor(dsum, 1);
    dsum += __shfl_xor(dsum, 2);
    dsum += __shfl_xor(dsum, 4);
    dsum += __shfl_xor(dsum, 8);
    dsum += __shfl_xor(dsum, 16);
    dsum += __shfl_xor(dsum, 32);
    if (lane == 0) atomicAdd(diagsum, dsum);
  }

#pragma unroll
  for (int m = 0; m < 4; ++m)
#pragma unroll
    for (int r = 0; r < 4; ++r) {
      float v = rowacc[m][r];
      v += __shfl_xor(v, 1);
      v += __shfl_xor(v, 2);
      v += __shfl_xor(v, 4);
      v += __shfl_xor(v, 8);
      if (lm == 0)
        atomicAdd(&rowsum[brow * BM + wm * 64 + m * 16 + lk * 4 + r], v);
    }
#pragma unroll
  for (int n = 0; n < 4; ++n) {
    float v = colacc[n];
    v += __shfl_xor(v, 16);
    v += __shfl_xor(v, 32);
    if (lk == 0)
      atomicAdd(&colsum[bcol * BN + wn * 64 + n * 16 + lm], v);
  }
}

__global__ __launch_bounds__(256) void clip_final(
    const float* __restrict__ rowsum, const float* __restrict__ colsum,
    const float* __restrict__ diagsum, float* __restrict__ out) {
  __shared__ double sdata[256];
  double s = 0.0;
  for (int i = threadIdx.x; i < NN; i += 256)
    s += (double)logf(rowsum[i]) + (double)logf(colsum[i]);
  sdata[threadIdx.x] = s;
  __syncthreads();
  for (int st = 128; st > 0; st >>= 1) {
    if ((int)threadIdx.x < st) sdata[threadIdx.x] += sdata[threadIdx.x + st];
    __syncthreads();
  }
  if (threadIdx.x == 0) {
    double loss = (double)SHIFT_C + sdata[0] * 0.5 / (double)NN
                - (double)diagsum[0] / (double)NN;
    out[0] = (float)loss;
  }
}

extern "C" void kernel_launch(void* const* d_in, const int* in_sizes, int n_in,
                              void* d_out, int out_size, void* d_ws, size_t ws_size,
                              hipStream_t stream) {
  const float* X = (const float*)d_in[0];
  const float* Y = (const float*)d_in[1];

  const size_t bf16_bytes = (size_t)2 * NN * DD * sizeof(unsigned short);  // 16 MB
  const size_t stats_bytes = (size_t)(2 * NN + 1) * sizeof(float);

  if (ws_size >= bf16_bytes + stats_bytes) {
    unsigned short* Xb = (unsigned short*)d_ws;
    unsigned short* Yb = Xb + (size_t)NN * DD;
    float* rowsum = (float*)((unsigned char*)d_ws + bf16_bytes);
    float* colsum = rowsum + NN;
    float* diagsum = colsum + NN;

    hipMemsetAsync(rowsum, 0, stats_bytes, stream);
    cvt_kernel<<<dim3(2 * NN * DD / 8 / 256), dim3(256), 0, stream>>>(X, Y, Xb, Yb);
    clip_gemm<<<dim3((NN / BM) * (NN / BN)), dim3(THREADS), 0, stream>>>(
        Xb, Yb, rowsum, colsum, diagsum);
    clip_final<<<dim3(1), dim3(256), 0, stream>>>(rowsum, colsum, diagsum, (float*)d_out);
  } else {
    float* rowsum = (float*)d_ws;
    float* colsum = rowsum + NN;
    float* diagsum = colsum + NN;
    hipMemsetAsync(d_ws, 0, stats_bytes, stream);
    clip_main_fb<<<dim3((NN / BM) * (NN / BN)), dim3(THREADS), 0, stream>>>(
        X, Y, rowsum, colsum, diagsum);
    clip_final<<<dim3(1), dim3(256), 0, stream>>>(rowsum, colsum, diagsum, (float*)d_out);
  }
}

// Round 5
// 295.882 us; speedup vs baseline: 1.4893x; 1.4893x over previous
//
#include <hip/hip_runtime.h>
#include <hip/hip_bf16.h>

#define NN 16384
#define DD 256
#define BM 128
#define BN 128
#define BK32 32
#define NKS8 8                 // 256 / 32
#define THREADS 256
#define SHIFT_C 64.0f
#define LOG2E 1.4426950408889634f

typedef __attribute__((ext_vector_type(4))) float f32x4;
typedef __attribute__((ext_vector_type(8))) short bf16x8;

#if __has_builtin(__builtin_amdgcn_exp2f)
#define EXP2F(x) __builtin_amdgcn_exp2f(x)
#else
#define EXP2F(x) exp2f(x)
#endif

__device__ __forceinline__ unsigned pkbf(float a, float b) {
  float2 t; t.x = a; t.y = b;
  __hip_bfloat162 h = __float22bfloat162_rn(t);
  union { __hip_bfloat162 h; unsigned u; } cv;
  cv.h = h;
  return cv.u;
}

// ---------------- pre-convert f32 -> bf16 ----------------
__global__ __launch_bounds__(256) void cvt_kernel(
    const float* __restrict__ X, const float* __restrict__ Y,
    unsigned short* __restrict__ Xb, unsigned short* __restrict__ Yb) {
  const int groups_per_arr = NN * DD / 8;
  int g = blockIdx.x * 256 + threadIdx.x;
  const float* src;
  unsigned short* dst;
  if (g < groups_per_arr) { src = X; dst = Xb; }
  else { src = Y; dst = Yb; g -= groups_per_arr; }
  float4 a = ((const float4*)src)[(size_t)g * 2];
  float4 b = ((const float4*)src)[(size_t)g * 2 + 1];
  uint4 p = { pkbf(a.x, a.y), pkbf(a.z, a.w), pkbf(b.x, b.y), pkbf(b.z, b.w) };
  ((uint4*)dst)[g] = p;
}

// ---------------- main fused GEMM + softmax-stats ----------------
// R3 structure + ONE change: pipelined staging with counted vmcnt (T4).
// BK=32, double-buffered A/B LDS (2x8KB each = 32KB total, occupancy kept),
// stage ks+2 after the read-done barrier; raw s_barrier; s_waitcnt vmcnt(4)
// in steady state (never 0 until last tile) so one stage is always in flight.
__global__ __launch_bounds__(THREADS) void clip_gemm(
    const unsigned short* __restrict__ Xb, const unsigned short* __restrict__ Yb,
    float* __restrict__ rowsum, float* __restrict__ colsum,
    float* __restrict__ diagsum) {
  __shared__ __align__(16) unsigned char smA[2 * 8192];
  __shared__ __align__(16) unsigned char smB[2 * 8192];

  const int tid = threadIdx.x;
  const int bid = blockIdx.x;
  // 2-level XCD-aware swizzle (L2-resident 2MB X/Y panels per XCD)
  const int xcd = bid & 7;
  const int t = bid >> 3;
  const int st = t >> 8;
  const int idx = t & 255;
  const int brow = xcd * 16 + (idx >> 4);
  const int bcol = st * 16 + (idx & 15);

  const unsigned short* xb = Xb + (size_t)brow * BM * DD;
  const unsigned short* yb = Yb + (size_t)bcol * BN * DD;

  const int wid = tid >> 6, lane = tid & 63;
  const int wm = wid >> 1, wn = wid & 1;
  const int lm = lane & 15, lk = lane >> 4;

  // staging: 512 slots of 16B per tile; 2 per thread (i=0,1)
  // slot s -> row = s>>2, linear subslot = s&3; source subslot ^= (row>>1)&3
  int srcoff[2], ldsoff[2];
#pragma unroll
  for (int i = 0; i < 2; ++i) {
    const int s = i * 256 + tid;
    const int row = s >> 2;
    const int g = (s & 3) ^ ((row >> 1) & 3);
    srcoff[i] = row * DD + g * 8;  // elements
    ldsoff[i] = s * 16;            // bytes, linear dest
  }

  f32x4 acc[4][4] = {};

#define STAGE(ks, buf)                                                         \
  {                                                                            \
    _Pragma("unroll")                                                          \
    for (int i = 0; i < 2; ++i) {                                              \
      __builtin_amdgcn_global_load_lds(                                        \
          (const __attribute__((address_space(1))) unsigned*)(xb + srcoff[i] + (ks) * BK32), \
          (__attribute__((address_space(3))) unsigned*)(smA + (buf) * 8192 + ldsoff[i]), \
          16, 0, 0);                                                           \
      __builtin_amdgcn_global_load_lds(                                        \
          (const __attribute__((address_space(1))) unsigned*)(yb + srcoff[i] + (ks) * BK32), \
          (__attribute__((address_space(3))) unsigned*)(smB + (buf) * 8192 + ldsoff[i]), \
          16, 0, 0);                                                           \
    }                                                                          \
  }

#define VMCNT4 asm volatile("s_waitcnt vmcnt(4)" ::: "memory")
#define VMCNT0 asm volatile("s_waitcnt vmcnt(0)" ::: "memory")
#define BAR    asm volatile("s_barrier" ::: "memory")

  // prologue: two tiles in flight
  STAGE(0, 0);
  STAGE(1, 1);

  const int rxor = ((lm >> 1) & 3) << 4;  // read-side swizzle (row>>1)&3 == (lm>>1)&3
  const int koff = (lk << 4);

#pragma unroll
  for (int ks = 0; ks < NKS8; ++ks) {
    const int cur = ks & 1;
    if (ks < NKS8 - 1) { VMCNT4; } else { VMCNT0; }  // drain tile ks only
    BAR;                                             // all waves have tile ks
    bf16x8 a[4], b[4];
#pragma unroll
    for (int m = 0; m < 4; ++m)
      a[m] = *(const bf16x8*)(smA + cur * 8192 + (wm * 64 + m * 16 + lm) * 64 + (koff ^ rxor));
#pragma unroll
    for (int n = 0; n < 4; ++n)
      b[n] = *(const bf16x8*)(smB + cur * 8192 + (wn * 64 + n * 16 + lm) * 64 + (koff ^ rxor));
#pragma unroll
    for (int m = 0; m < 4; ++m)
#pragma unroll
      for (int n = 0; n < 4; ++n)
        acc[m][n] = __builtin_amdgcn_mfma_f32_16x16x32_bf16(a[m], b[n], acc[m][n], 0, 0, 0);
    BAR;                                             // all waves done reading buf[cur]
    if (ks + 2 < NKS8) { STAGE(ks + 2, cur); }       // overwrite now-free buffer
  }
#undef STAGE
#undef VMCNT4
#undef VMCNT0
#undef BAR

  // ---- fused softmax-statistics epilogue ----
  float rowacc[4][4];
  float colacc[4];
#pragma unroll
  for (int m = 0; m < 4; ++m)
#pragma unroll
    for (int r = 0; r < 4; ++r) rowacc[m][r] = 0.f;
#pragma unroll
  for (int n = 0; n < 4; ++n) colacc[n] = 0.f;

  const float negC = -(SHIFT_C * LOG2E);
#pragma unroll
  for (int m = 0; m < 4; ++m)
#pragma unroll
    for (int n = 0; n < 4; ++n)
#pragma unroll
      for (int r = 0; r < 4; ++r) {
        float e = EXP2F(__builtin_fmaf(acc[m][n][r], LOG2E, negC));
        rowacc[m][r] += e;
        colacc[n] += e;
      }

  if (brow == bcol && wm == wn) {
    float dsum = 0.f;
#pragma unroll
    for (int m = 0; m < 4; ++m)
#pragma unroll
      for (int n = 0; n < 4; ++n)
#pragma unroll
        for (int r = 0; r < 4; ++r) {
          const int rr = m * 16 + lk * 4 + r;
          const int cc = n * 16 + lm;
          if (rr == cc) dsum += acc[m][n][r];
        }
    dsum += __shfl_xor(dsum, 1);
    dsum += __shfl_xor(dsum, 2);
    dsum += __shfl_xor(dsum, 4);
    dsum += __shfl_xor(dsum, 8);
    dsum += __shfl_xor(dsum, 16);
    dsum += __shfl_xor(dsum, 32);
    if (lane == 0) atomicAdd(diagsum, dsum);
  }

#pragma unroll
  for (int m = 0; m < 4; ++m)
#pragma unroll
    for (int r = 0; r < 4; ++r) {
      float v = rowacc[m][r];
      v += __shfl_xor(v, 1);
      v += __shfl_xor(v, 2);
      v += __shfl_xor(v, 4);
      v += __shfl_xor(v, 8);
      if (lm == 0)
        atomicAdd(&rowsum[brow * BM + wm * 64 + m * 16 + lk * 4 + r], v);
    }
#pragma unroll
  for (int n = 0; n < 4; ++n) {
    float v = colacc[n];
    v += __shfl_xor(v, 16);
    v += __shfl_xor(v, 32);
    if (lk == 0)
      atomicAdd(&colsum[bcol * BN + wn * 64 + n * 16 + lm], v);
  }
}

// ---------------- fallback (reg-staging, no ws bf16 buffers) ----------------
__global__ __launch_bounds__(THREADS) void clip_main_fb(
    const float* __restrict__ X, const float* __restrict__ Y,
    float* __restrict__ rowsum, float* __restrict__ colsum,
    float* __restrict__ diagsum) {
  __shared__ __align__(16) unsigned char smem[2 * BM * 64 * 2];
  unsigned char* smA = smem;
  unsigned char* smB = smem + BM * 64 * 2;

  const int tid = threadIdx.x;
  const int bid = blockIdx.x;
  const int swz = (bid & 7) * 2048 + (bid >> 3);
  const int brow = swz >> 7;
  const int bcol = swz & 127;

  const float* xb = X + (size_t)brow * BM * DD;
  const float* yb = Y + (size_t)bcol * BN * DD;

  const int wid = tid >> 6, lane = tid & 63;
  const int wm = wid >> 1, wn = wid & 1;
  const int lm = lane & 15, lk = lane >> 4;

  f32x4 acc[4][4] = {};

  for (int ks = 0; ks < 4; ++ks) {
    const int kbase = ks * 64;
    if (ks) __syncthreads();
#pragma unroll
    for (int i = 0; i < 4; ++i) {
      const int c = tid + i * THREADS;
      const int row = c >> 3, slot = c & 7;
      const int boff = row * 128 + ((slot << 4) ^ ((row & 7) << 4));
      const float* ga = xb + row * DD + kbase + (slot << 3);
      float4 a0 = *(const float4*)ga;
      float4 a1 = *(const float4*)(ga + 4);
      uint4 pa = { pkbf(a0.x, a0.y), pkbf(a0.z, a0.w),
                   pkbf(a1.x, a1.y), pkbf(a1.z, a1.w) };
      *(uint4*)(smA + boff) = pa;
      const float* gb = yb + row * DD + kbase + (slot << 3);
      float4 b0 = *(const float4*)gb;
      float4 b1 = *(const float4*)(gb + 4);
      uint4 pb = { pkbf(b0.x, b0.y), pkbf(b0.z, b0.w),
                   pkbf(b1.x, b1.y), pkbf(b1.z, b1.w) };
      *(uint4*)(smB + boff) = pb;
    }
    __syncthreads();

#pragma unroll
    for (int kk = 0; kk < 2; ++kk) {
      const int kboff = kk * 64 + lk * 16;
      bf16x8 a[4], b[4];
#pragma unroll
      for (int m = 0; m < 4; ++m) {
        const int row = wm * 64 + m * 16 + lm;
        a[m] = *(const bf16x8*)(smA + row * 128 + (kboff ^ ((row & 7) << 4)));
      }
#pragma unroll
      for (int n = 0; n < 4; ++n) {
        const int row = wn * 64 + n * 16 + lm;
        b[n] = *(const bf16x8*)(smB + row * 128 + (kboff ^ ((row & 7) << 4)));
      }
#pragma unroll
      for (int m = 0; m < 4; ++m)
#pragma unroll
        for (int n = 0; n < 4; ++n)
          acc[m][n] = __builtin_amdgcn_mfma_f32_16x16x32_bf16(a[m], b[n], acc[m][n], 0, 0, 0);
    }
  }

  float rowacc[4][4];
  float colacc[4];
#pragma unroll
  for (int m = 0; m < 4; ++m)
#pragma unroll
    for (int r = 0; r < 4; ++r) rowacc[m][r] = 0.f;
#pragma unroll
  for (int n = 0; n < 4; ++n) colacc[n] = 0.f;

  const float negC = -(SHIFT_C * LOG2E);
#pragma unroll
  for (int m = 0; m < 4; ++m)
#pragma unroll
    for (int n = 0; n < 4; ++n)
#pragma unroll
      for (int r = 0; r < 4; ++r) {
        float e = EXP2F(__builtin_fmaf(acc[m][n][r], LOG2E, negC));
        rowacc[m][r] += e;
        colacc[n] += e;
      }

  if (brow == bcol && wm == wn) {
    float dsum = 0.f;
#pragma unroll
    for (int m = 0; m < 4; ++m)
#pragma unroll
      for (int n = 0; n < 4; ++n)
#pragma unroll
        for (int r = 0; r < 4; ++r) {
          const int rr = m * 16 + lk * 4 + r;
          const int cc = n * 16 + lm;
          if (rr == cc) dsum += acc[m][n][r];
        }
    dsum += __shfl_xor(dsum, 1);
    dsum += __shfl_xor(dsum, 2);
    dsum += __shfl_xor(dsum, 4);
    dsum += __shfl_xor(dsum, 8);
    dsum += __shfl_xor(dsum, 16);
    dsum += __shfl_xor(dsum, 32);
    if (lane == 0) atomicAdd(diagsum, dsum);
  }

#pragma unroll
  for (int m = 0; m < 4; ++m)
#pragma unroll
    for (int r = 0; r < 4; ++r) {
      float v = rowacc[m][r];
      v += __shfl_xor(v, 1);
      v += __shfl_xor(v, 2);
      v += __shfl_xor(v, 4);
      v += __shfl_xor(v, 8);
      if (lm == 0)
        atomicAdd(&rowsum[brow * BM + wm * 64 + m * 16 + lk * 4 + r], v);
    }
#pragma unroll
  for (int n = 0; n < 4; ++n) {
    float v = colacc[n];
    v += __shfl_xor(v, 16);
    v += __shfl_xor(v, 32);
    if (lk == 0)
      atomicAdd(&colsum[bcol * BN + wn * 64 + n * 16 + lm], v);
  }
}

__global__ __launch_bounds__(256) void clip_final(
    const float* __restrict__ rowsum, const float* __restrict__ colsum,
    const float* __restrict__ diagsum, float* __restrict__ out) {
  __shared__ double sdata[256];
  double s = 0.0;
  for (int i = threadIdx.x; i < NN; i += 256)
    s += (double)logf(rowsum[i]) + (double)logf(colsum[i]);
  sdata[threadIdx.x] = s;
  __syncthreads();
  for (int st = 128; st > 0; st >>= 1) {
    if ((int)threadIdx.x < st) sdata[threadIdx.x] += sdata[threadIdx.x + st];
    __syncthreads();
  }
  if (threadIdx.x == 0) {
    double loss = (double)SHIFT_C + sdata[0] * 0.5 / (double)NN
                - (double)diagsum[0] / (double)NN;
    out[0] = (float)loss;
  }
}

extern "C" void kernel_launch(void* const* d_in, const int* in_sizes, int n_in,
                              void* d_out, int out_size, void* d_ws, size_t ws_size,
                              hipStream_t stream) {
  const float* X = (const float*)d_in[0];
  const float* Y = (const float*)d_in[1];

  const size_t bf16_bytes = (size_t)2 * NN * DD * sizeof(unsigned short);  // 16 MB
  const size_t stats_bytes = (size_t)(2 * NN + 1) * sizeof(float);

  if (ws_size >= bf16_bytes + stats_bytes) {
    unsigned short* Xb = (unsigned short*)d_ws;
    unsigned short* Yb = Xb + (size_t)NN * DD;
    float* rowsum = (float*)((unsigned char*)d_ws + bf16_bytes);
    float* colsum = rowsum + NN;
    float* diagsum = colsum + NN;

    hipMemsetAsync(rowsum, 0, stats_bytes, stream);
    cvt_kernel<<<dim3(2 * NN * DD / 8 / 256), dim3(256), 0, stream>>>(X, Y, Xb, Yb);
    clip_gemm<<<dim3((NN / BM) * (NN / BN)), dim3(THREADS), 0, stream>>>(
        Xb, Yb, rowsum, colsum, diagsum);
    clip_final<<<dim3(1), dim3(256), 0, stream>>>(rowsum, colsum, diagsum, (float*)d_out);
  } else {
    float* rowsum = (float*)d_ws;
    float* colsum = rowsum + NN;
    float* diagsum = colsum + NN;
    hipMemsetAsync(d_ws, 0, stats_bytes, stream);
    clip_main_fb<<<dim3((NN / BM) * (NN / BN)), dim3(THREADS), 0, stream>>>(
        X, Y, rowsum, colsum, diagsum);
    clip_final<<<dim3(1), dim3(256), 0, stream>>>(rowsum, colsum, diagsum, (float*)d_out);
  }
}

// Round 6
// 285.978 us; speedup vs baseline: 1.5408x; 1.0346x over previous
//
#include <hip/hip_runtime.h>
#include <hip/hip_bf16.h>

#define NN 16384
#define DD 256
#define BM 256
#define BN 256
#define BK 32
#define NKT 8                  // 256 / 32 K-tiles
#define THREADS 512
#define SHIFT_C 64.0f
#define LOG2E 1.4426950408889634f

typedef __attribute__((ext_vector_type(4))) float f32x4;
typedef __attribute__((ext_vector_type(8))) short bf16x8;

#if __has_builtin(__builtin_amdgcn_exp2f)
#define EXP2F(x) __builtin_amdgcn_exp2f(x)
#else
#define EXP2F(x) exp2f(x)
#endif

__device__ __forceinline__ unsigned pkbf(float a, float b) {
  float2 t; t.x = a; t.y = b;
  __hip_bfloat162 h = __float22bfloat162_rn(t);
  union { __hip_bfloat162 h; unsigned u; } cv;
  cv.h = h;
  return cv.u;
}

// ---------------- pre-convert f32 -> bf16 ----------------
__global__ __launch_bounds__(256) void cvt_kernel(
    const float* __restrict__ X, const float* __restrict__ Y,
    unsigned short* __restrict__ Xb, unsigned short* __restrict__ Yb) {
  const int groups_per_arr = NN * DD / 8;
  int g = blockIdx.x * 256 + threadIdx.x;
  const float* src;
  unsigned short* dst;
  if (g < groups_per_arr) { src = X; dst = Xb; }
  else { src = Y; dst = Yb; g -= groups_per_arr; }
  float4 a = ((const float4*)src)[(size_t)g * 2];
  float4 b = ((const float4*)src)[(size_t)g * 2 + 1];
  uint4 p = { pkbf(a.x, a.y), pkbf(a.z, a.w), pkbf(b.x, b.y), pkbf(b.z, b.w) };
  ((uint4*)dst)[g] = p;
}

// ---------------- main fused GEMM + softmax-stats ----------------
// 256x256 tile, 8 waves (2Mx4N), BK=32, 3-deep LDS pipeline (96KB), 2 phases
// per K-tile, counted vmcnt(4) at tile entry (never 0 until tail), setprio
// around MFMA clusters. Stage of K-tile t+2 issued during tile t => every
// global_load_lds has ~2 K-tiles of compute to land.
__global__ __launch_bounds__(THREADS, 2) void clip_gemm(
    const unsigned short* __restrict__ Xb, const unsigned short* __restrict__ Yb,
    float* __restrict__ rowsum, float* __restrict__ colsum,
    float* __restrict__ diagsum) {
  // sm[buf][A:16KB | B:16KB], 3 bufs = 96KB
  __shared__ __align__(16) unsigned char sm[3 * 32768];

  const int tid = threadIdx.x;
  const int bid = blockIdx.x;
  // bijective 2-level XCD swizzle: 4096 blocks = 8 xcd x 8 col-panels x 64
  const int xcd = bid & 7;
  const int t0 = bid >> 3;       // 0..511
  const int stp = t0 >> 6;       // 8 col-panels
  const int idx = t0 & 63;
  const int brow = xcd * 8 + (idx >> 3);   // 0..63
  const int bcol = stp * 8 + (idx & 7);    // 0..63

  const unsigned short* xb = Xb + (size_t)brow * BM * DD;
  const unsigned short* yb = Yb + (size_t)bcol * BN * DD;

  const int wid = tid >> 6, lane = tid & 63;
  const int wm = wid >> 2, wn = wid & 3;   // 2 x 4 waves; wave owns 128x64
  const int lm = lane & 15, lk = lane >> 4;

  // staging: per K-tile, per array: 256 rows x 64B = 1024 slots of 16B;
  // thread stages slots s = i*512+tid (i=0,1), one (A,B) pair per phase i.
  // source subslot pre-swizzled with involution (s&3)^((s>>2)&3)^((s>>4)&3).
  int srcElem[2], ldsb[2];
#pragma unroll
  for (int i = 0; i < 2; ++i) {
    const int s = i * 512 + tid;
    const int row = s >> 2;
    const int g = (s & 3) ^ (row & 3) ^ ((row >> 2) & 3);
    srcElem[i] = row * DD + g * 8;  // elements
    ldsb[i] = s * 16;               // linear LDS dest bytes
  }

  // read-side swizzle: subslot = lk ^ (row&3) ^ ((row>>2)&3), row=16*m+lm
  const int rsw = (lk ^ (lm & 3) ^ (lm >> 2)) << 4;

  f32x4 acc[8][4] = {};

#define STAGE_QS(t, i)                                                         \
  {                                                                            \
    __builtin_amdgcn_global_load_lds(                                          \
        (const __attribute__((address_space(1))) unsigned*)(xb + srcElem[i] + (t) * BK), \
        (__attribute__((address_space(3))) unsigned*)(sm + ((t) % 3) * 32768 + ldsb[i]), \
        16, 0, 0);                                                             \
    __builtin_amdgcn_global_load_lds(                                          \
        (const __attribute__((address_space(1))) unsigned*)(yb + srcElem[i] + (t) * BK), \
        (__attribute__((address_space(3))) unsigned*)(sm + ((t) % 3) * 32768 + 16384 + ldsb[i]), \
        16, 0, 0);                                                             \
  }

  // prologue: two K-tiles in flight (8 loads/thread)
  STAGE_QS(0, 0); STAGE_QS(0, 1);
  STAGE_QS(1, 0); STAGE_QS(1, 1);

#pragma unroll
  for (int t = 0; t < NKT; ++t) {
    // tile entry: own stage of t retired (in-order); others' via barrier
    if (t < NKT - 1) { asm volatile("s_waitcnt vmcnt(4)" ::: "memory"); }
    else             { asm volatile("s_waitcnt vmcnt(0)" ::: "memory"); }
    __builtin_amdgcn_s_barrier();
    const unsigned char* bufA = sm + (t % 3) * 32768;
    const unsigned char* bufB = bufA + 16384;
#pragma unroll
    for (int ph = 0; ph < 2; ++ph) {
      bf16x8 a[4], b[4];
#pragma unroll
      for (int mm = 0; mm < 4; ++mm) {
        const int row = wm * 128 + (ph * 4 + mm) * 16 + lm;
        a[mm] = *(const bf16x8*)(bufA + row * 64 + rsw);
      }
#pragma unroll
      for (int nn = 0; nn < 4; ++nn) {
        const int row = wn * 64 + nn * 16 + lm;
        b[nn] = *(const bf16x8*)(bufB + row * 64 + rsw);
      }
      if (t + 2 < NKT) { STAGE_QS(t + 2, ph); }  // writes buf (t-1)%3: readers done
      if (ph == 1) break;                        // phase-1 barrier is next tile's entry
      asm volatile("s_waitcnt lgkmcnt(0)" ::: "memory");
      __builtin_amdgcn_sched_barrier(0);
      __builtin_amdgcn_s_setprio(1);
#pragma unroll
      for (int mm = 0; mm < 4; ++mm)
#pragma unroll
        for (int nn = 0; nn < 4; ++nn)
          acc[0 * 4 + mm][nn] = __builtin_amdgcn_mfma_f32_16x16x32_bf16(a[mm], b[nn], acc[0 * 4 + mm][nn], 0, 0, 0);
      __builtin_amdgcn_s_setprio(0);
      __builtin_amdgcn_s_barrier();
    }
    // phase 1 compute (separated so the value dependency keeps a/b of ph=1)
    {
      bf16x8 a[4], b[4];
#pragma unroll
      for (int mm = 0; mm < 4; ++mm) {
        const int row = wm * 128 + (1 * 4 + mm) * 16 + lm;
        a[mm] = *(const bf16x8*)(bufA + row * 64 + rsw);
      }
#pragma unroll
      for (int nn = 0; nn < 4; ++nn) {
        const int row = wn * 64 + nn * 16 + lm;
        b[nn] = *(const bf16x8*)(bufB + row * 64 + rsw);
      }
      asm volatile("s_waitcnt lgkmcnt(0)" ::: "memory");
      __builtin_amdgcn_sched_barrier(0);
      __builtin_amdgcn_s_setprio(1);
#pragma unroll
      for (int mm = 0; mm < 4; ++mm)
#pragma unroll
        for (int nn = 0; nn < 4; ++nn)
          acc[4 + mm][nn] = __builtin_amdgcn_mfma_f32_16x16x32_bf16(a[mm], b[nn], acc[4 + mm][nn], 0, 0, 0);
      __builtin_amdgcn_s_setprio(0);
    }
  }
#undef STAGE_QS

  // ---- fused softmax-statistics epilogue ----
  float rowacc[8][4];
  float colacc[4];
#pragma unroll
  for (int m = 0; m < 8; ++m)
#pragma unroll
    for (int r = 0; r < 4; ++r) rowacc[m][r] = 0.f;
#pragma unroll
  for (int n = 0; n < 4; ++n) colacc[n] = 0.f;

  const float negC = -(SHIFT_C * LOG2E);
#pragma unroll
  for (int m = 0; m < 8; ++m)
#pragma unroll
    for (int n = 0; n < 4; ++n)
#pragma unroll
      for (int r = 0; r < 4; ++r) {
        float e = EXP2F(__builtin_fmaf(acc[m][n][r], LOG2E, negC));
        rowacc[m][r] += e;
        colacc[n] += e;
      }

  // diagonal: wave covers rows [wm*128,+128), cols [wn*64,+64)
  if (brow == bcol && (wn >> 1) == wm) {
    float dsum = 0.f;
#pragma unroll
    for (int m = 0; m < 8; ++m)
#pragma unroll
      for (int n = 0; n < 4; ++n)
#pragma unroll
        for (int r = 0; r < 4; ++r) {
          const int rr = wm * 128 + m * 16 + lk * 4 + r;
          const int cc = wn * 64 + n * 16 + lm;
          if (rr == cc) dsum += acc[m][n][r];
        }
    dsum += __shfl_xor(dsum, 1);
    dsum += __shfl_xor(dsum, 2);
    dsum += __shfl_xor(dsum, 4);
    dsum += __shfl_xor(dsum, 8);
    dsum += __shfl_xor(dsum, 16);
    dsum += __shfl_xor(dsum, 32);
    if (lane == 0) atomicAdd(diagsum, dsum);
  }

  // row sums: reduce across lm (lane&15)
#pragma unroll
  for (int m = 0; m < 8; ++m)
#pragma unroll
    for (int r = 0; r < 4; ++r) {
      float v = rowacc[m][r];
      v += __shfl_xor(v, 1);
      v += __shfl_xor(v, 2);
      v += __shfl_xor(v, 4);
      v += __shfl_xor(v, 8);
      if (lm == 0)
        atomicAdd(&rowsum[brow * BM + wm * 128 + m * 16 + lk * 4 + r], v);
    }
  // col sums: reduce across lk (lane>>4)
#pragma unroll
  for (int n = 0; n < 4; ++n) {
    float v = colacc[n];
    v += __shfl_xor(v, 16);
    v += __shfl_xor(v, 32);
    if (lk == 0)
      atomicAdd(&colsum[bcol * BN + wn * 64 + n * 16 + lm], v);
  }
}

// ---------------- fallback (reg-staging, no ws bf16 buffers) ----------------
__global__ __launch_bounds__(256) void clip_main_fb(
    const float* __restrict__ X, const float* __restrict__ Y,
    float* __restrict__ rowsum, float* __restrict__ colsum,
    float* __restrict__ diagsum) {
  __shared__ __align__(16) unsigned char smem[2 * 128 * 64 * 2];
  unsigned char* smA = smem;
  unsigned char* smB = smem + 128 * 64 * 2;

  const int tid = threadIdx.x;
  const int bid = blockIdx.x;
  const int swz = (bid & 7) * 2048 + (bid >> 3);
  const int brow = swz >> 7;
  const int bcol = swz & 127;

  const float* xb = X + (size_t)brow * 128 * DD;
  const float* yb = Y + (size_t)bcol * 128 * DD;

  const int wid = tid >> 6, lane = tid & 63;
  const int wm = wid >> 1, wn = wid & 1;
  const int lm = lane & 15, lk = lane >> 4;

  f32x4 acc[4][4] = {};

  for (int ks = 0; ks < 4; ++ks) {
    const int kbase = ks * 64;
    if (ks) __syncthreads();
#pragma unroll
    for (int i = 0; i < 4; ++i) {
      const int c = tid + i * 256;
      const int row = c >> 3, slot = c & 7;
      const int boff = row * 128 + ((slot << 4) ^ ((row & 7) << 4));
      const float* ga = xb + row * DD + kbase + (slot << 3);
      float4 a0 = *(const float4*)ga;
      float4 a1 = *(const float4*)(ga + 4);
      uint4 pa = { pkbf(a0.x, a0.y), pkbf(a0.z, a0.w),
                   pkbf(a1.x, a1.y), pkbf(a1.z, a1.w) };
      *(uint4*)(smA + boff) = pa;
      const float* gb = yb + row * DD + kbase + (slot << 3);
      float4 b0 = *(const float4*)gb;
      float4 b1 = *(const float4*)(gb + 4);
      uint4 pb = { pkbf(b0.x, b0.y), pkbf(b0.z, b0.w),
                   pkbf(b1.x, b1.y), pkbf(b1.z, b1.w) };
      *(uint4*)(smB + boff) = pb;
    }
    __syncthreads();

#pragma unroll
    for (int kk = 0; kk < 2; ++kk) {
      const int kboff = kk * 64 + lk * 16;
      bf16x8 a[4], b[4];
#pragma unroll
      for (int m = 0; m < 4; ++m) {
        const int row = wm * 64 + m * 16 + lm;
        a[m] = *(const bf16x8*)(smA + row * 128 + (kboff ^ ((row & 7) << 4)));
      }
#pragma unroll
      for (int n = 0; n < 4; ++n) {
        const int row = wn * 64 + n * 16 + lm;
        b[n] = *(const bf16x8*)(smB + row * 128 + (kboff ^ ((row & 7) << 4)));
      }
#pragma unroll
      for (int m = 0; m < 4; ++m)
#pragma unroll
        for (int n = 0; n < 4; ++n)
          acc[m][n] = __builtin_amdgcn_mfma_f32_16x16x32_bf16(a[m], b[n], acc[m][n], 0, 0, 0);
    }
  }

  float rowacc[4][4];
  float colacc[4];
#pragma unroll
  for (int m = 0; m < 4; ++m)
#pragma unroll
    for (int r = 0; r < 4; ++r) rowacc[m][r] = 0.f;
#pragma unroll
  for (int n = 0; n < 4; ++n) colacc[n] = 0.f;

  const float negC = -(SHIFT_C * LOG2E);
#pragma unroll
  for (int m = 0; m < 4; ++m)
#pragma unroll
    for (int n = 0; n < 4; ++n)
#pragma unroll
      for (int r = 0; r < 4; ++r) {
        float e = EXP2F(__builtin_fmaf(acc[m][n][r], LOG2E, negC));
        rowacc[m][r] += e;
        colacc[n] += e;
      }

  if (brow == bcol && wm == wn) {
    float dsum = 0.f;
#pragma unroll
    for (int m = 0; m < 4; ++m)
#pragma unroll
      for (int n = 0; n < 4; ++n)
#pragma unroll
        for (int r = 0; r < 4; ++r) {
          const int rr = m * 16 + lk * 4 + r;
          const int cc = n * 16 + lm;
          if (rr == cc) dsum += acc[m][n][r];
        }
    dsum += __shfl_xor(dsum, 1);
    dsum += __shfl_xor(dsum, 2);
    dsum += __shfl_xor(dsum, 4);
    dsum += __shfl_xor(dsum, 8);
    dsum += __shfl_xor(dsum, 16);
    dsum += __shfl_xor(dsum, 32);
    if (lane == 0) atomicAdd(diagsum, dsum);
  }

#pragma unroll
  for (int m = 0; m < 4; ++m)
#pragma unroll
    for (int r = 0; r < 4; ++r) {
      float v = rowacc[m][r];
      v += __shfl_xor(v, 1);
      v += __shfl_xor(v, 2);
      v += __shfl_xor(v, 4);
      v += __shfl_xor(v, 8);
      if (lm == 0)
        atomicAdd(&rowsum[brow * 128 + wm * 64 + m * 16 + lk * 4 + r], v);
    }
#pragma unroll
  for (int n = 0; n < 4; ++n) {
    float v = colacc[n];
    v += __shfl_xor(v, 16);
    v += __shfl_xor(v, 32);
    if (lk == 0)
      atomicAdd(&colsum[bcol * 128 + wn * 64 + n * 16 + lm], v);
  }
}

__global__ __launch_bounds__(256) void clip_final(
    const float* __restrict__ rowsum, const float* __restrict__ colsum,
    const float* __restrict__ diagsum, float* __restrict__ out) {
  __shared__ double sdata[256];
  double s = 0.0;
  for (int i = threadIdx.x; i < NN; i += 256)
    s += (double)logf(rowsum[i]) + (double)logf(colsum[i]);
  sdata[threadIdx.x] = s;
  __syncthreads();
  for (int st = 128; st > 0; st >>= 1) {
    if ((int)threadIdx.x < st) sdata[threadIdx.x] += sdata[threadIdx.x + st];
    __syncthreads();
  }
  if (threadIdx.x == 0) {
    double loss = (double)SHIFT_C + sdata[0] * 0.5 / (double)NN
                - (double)diagsum[0] / (double)NN;
    out[0] = (float)loss;
  }
}

extern "C" void kernel_launch(void* const* d_in, const int* in_sizes, int n_in,
                              void* d_out, int out_size, void* d_ws, size_t ws_size,
                              hipStream_t stream) {
  const float* X = (const float*)d_in[0];
  const float* Y = (const float*)d_in[1];

  const size_t bf16_bytes = (size_t)2 * NN * DD * sizeof(unsigned short);  // 16 MB
  const size_t stats_bytes = (size_t)(2 * NN + 1) * sizeof(float);

  if (ws_size >= bf16_bytes + stats_bytes) {
    unsigned short* Xb = (unsigned short*)d_ws;
    unsigned short* Yb = Xb + (size_t)NN * DD;
    float* rowsum = (float*)((unsigned char*)d_ws + bf16_bytes);
    float* colsum = rowsum + NN;
    float* diagsum = colsum + NN;

    hipMemsetAsync(rowsum, 0, stats_bytes, stream);
    cvt_kernel<<<dim3(2 * NN * DD / 8 / 256), dim3(256), 0, stream>>>(X, Y, Xb, Yb);
    clip_gemm<<<dim3((NN / BM) * (NN / BN)), dim3(THREADS), 0, stream>>>(
        Xb, Yb, rowsum, colsum, diagsum);
    clip_final<<<dim3(1), dim3(256), 0, stream>>>(rowsum, colsum, diagsum, (float*)d_out);
  } else {
    float* rowsum = (float*)d_ws;
    float* colsum = rowsum + NN;
    float* diagsum = colsum + NN;
    hipMemsetAsync(d_ws, 0, stats_bytes, stream);
    clip_main_fb<<<dim3((NN / 128) * (NN / 128)), dim3(256), 0, stream>>>(
        X, Y, rowsum, colsum, diagsum);
    clip_final<<<dim3(1), dim3(256), 0, stream>>>(rowsum, colsum, diagsum, (float*)d_out);
  }
}

// Round 7
// 275.985 us; speedup vs baseline: 1.5966x; 1.0362x over previous
//
#include <hip/hip_runtime.h>
#include <hip/hip_bf16.h>

#define NN 16384
#define DD 256
#define BM 256
#define BN 256
#define BK 64
#define NKT 4                  // 256 / 64 K-tiles
#define THREADS 512
#define SHIFT_C 64.0f
#define LOG2E 1.4426950408889634f

typedef __attribute__((ext_vector_type(4))) float f32x4;
typedef __attribute__((ext_vector_type(8))) short bf16x8;

#if __has_builtin(__builtin_amdgcn_exp2f)
#define EXP2F(x) __builtin_amdgcn_exp2f(x)
#else
#define EXP2F(x) exp2f(x)
#endif

__device__ __forceinline__ unsigned pkbf(float a, float b) {
  float2 t; t.x = a; t.y = b;
  __hip_bfloat162 h = __float22bfloat162_rn(t);
  union { __hip_bfloat162 h; unsigned u; } cv;
  cv.h = h;
  return cv.u;
}

// ---------------- pre-convert f32 -> bf16 ----------------
__global__ __launch_bounds__(256) void cvt_kernel(
    const float* __restrict__ X, const float* __restrict__ Y,
    unsigned short* __restrict__ Xb, unsigned short* __restrict__ Yb) {
  const int groups_per_arr = NN * DD / 8;
  int g = blockIdx.x * 256 + threadIdx.x;
  const float* src;
  unsigned short* dst;
  if (g < groups_per_arr) { src = X; dst = Xb; }
  else { src = Y; dst = Yb; g -= groups_per_arr; }
  float4 a = ((const float4*)src)[(size_t)g * 2];
  float4 b = ((const float4*)src)[(size_t)g * 2 + 1];
  uint4 p = { pkbf(a.x, a.y), pkbf(a.z, a.w), pkbf(b.x, b.y), pkbf(b.z, b.w) };
  ((uint4*)dst)[g] = p;
}

// ---------------- main fused GEMM + softmax-stats ----------------
// m201-style 8-phase schedule: 256x256 tile, 8 waves (2Mx4N, wave=128x64),
// BK=64, 2x64KB LDS double-buffer, 128B rows with ^((row&7)<<4) swizzle
// (source-pre-swizzled for global_load_lds, rule #21). Per K-tile: 8 phases,
// each {ds_reads ; 1 stage-pair ; barrier ; lgkmcnt(0) ; setprio ; 8 MFMA ;
// setprio ; barrier}. Depth-1 prefetch into the other buffer, stage issued
// in phases 0-3 => ~4 phases of runway before the tile-entry vmcnt(0).
__global__ __launch_bounds__(THREADS, 2) void clip_gemm(
    const unsigned short* __restrict__ Xb, const unsigned short* __restrict__ Yb,
    float* __restrict__ rowsum, float* __restrict__ colsum,
    float* __restrict__ diagsum) {
  __shared__ __align__(16) unsigned char sm[2 * 65536];  // [buf][A:32K|B:32K]

  const int tid = threadIdx.x;
  const int bid = blockIdx.x;
  // bijective 2-level XCD swizzle: 4096 blocks = 8 xcd x 8 col-panels x 64
  const int xcd = bid & 7;
  const int t0 = bid >> 3;
  const int stp = t0 >> 6;
  const int idx = t0 & 63;
  const int brow = xcd * 8 + (idx >> 3);   // 0..63
  const int bcol = stp * 8 + (idx & 7);    // 0..63

  const unsigned short* xb = Xb + (size_t)brow * BM * DD;
  const unsigned short* yb = Yb + (size_t)bcol * BN * DD;

  const int wid = tid >> 6, lane = tid & 63;
  const int wm = wid >> 2, wn = wid & 3;   // wave owns rows [wm*128,+128) x cols [wn*64,+64)
  const int lm = lane & 15, lk = lane >> 4;

  // staging: per array 2048 slots of 16B ([256 rows][8 subslots]); 4/thread.
  // LDS slot (row, sl) holds source subslot g = sl ^ (row&7)  (involution).
  int sg[4], sd[4];
#pragma unroll
  for (int j = 0; j < 4; ++j) {
    const int s = j * 512 + tid;
    const int row = s >> 3;
    const int g = (s & 7) ^ (row & 7);
    sg[j] = row * DD + g * 8;   // source element offset (k-base added per tile)
    sd[j] = s * 16;             // linear LDS byte offset
  }

  f32x4 acc[8][4] = {};

#define GLOAD(t1, j)                                                           \
  {                                                                            \
    __builtin_amdgcn_global_load_lds(                                          \
        (const __attribute__((address_space(1))) unsigned*)(xb + sg[j] + (t1) * BK), \
        (__attribute__((address_space(3))) unsigned*)(sm + ((t1) & 1) * 65536 + sd[j]), \
        16, 0, 0);                                                             \
    __builtin_amdgcn_global_load_lds(                                          \
        (const __attribute__((address_space(1))) unsigned*)(yb + sg[j] + (t1) * BK), \
        (__attribute__((address_space(3))) unsigned*)(sm + ((t1) & 1) * 65536 + 32768 + sd[j]), \
        16, 0, 0);                                                             \
  }

  // prologue: stage tile 0 fully
  GLOAD(0, 0); GLOAD(0, 1); GLOAD(0, 2); GLOAD(0, 3);

#pragma unroll
  for (int t = 0; t < NKT; ++t) {
    // tile entry: this tile's stage (issued >=4 phases ago in steady state)
    asm volatile("s_waitcnt vmcnt(0)" ::: "memory");
    __builtin_amdgcn_s_barrier();
    const unsigned char* bA = sm + (t & 1) * 65536;
    const unsigned char* bB = bA + 32768;
    bf16x8 b[4];
#pragma unroll
    for (int p = 0; p < 8; ++p) {
      const int kh = p >> 2, mq = p & 3;
      const int sl = (((kh << 2) | lk) ^ (lm & 7)) << 4;  // swizzled subslot byte
      // ds-reads for THIS phase
      bf16x8 a0 = *(const bf16x8*)(bA + (wm * 128 + (2 * mq) * 16 + lm) * 128 + sl);
      bf16x8 a1 = *(const bf16x8*)(bA + (wm * 128 + (2 * mq + 1) * 16 + lm) * 128 + sl);
      if (mq == 0) {
#pragma unroll
        for (int nf = 0; nf < 4; ++nf)
          b[nf] = *(const bf16x8*)(bB + (wn * 64 + nf * 16 + lm) * 128 + sl);
      }
      // stage one slot-pair of tile t+1 into the OTHER buffer (phases 0-3)
      if (t < NKT - 1 && p < 4) { GLOAD(t + 1, p); }
      __builtin_amdgcn_s_barrier();
      asm volatile("s_waitcnt lgkmcnt(0)" ::: "memory");
      __builtin_amdgcn_sched_barrier(0);
      __builtin_amdgcn_s_setprio(1);
#pragma unroll
      for (int nf = 0; nf < 4; ++nf)
        acc[2 * mq][nf] = __builtin_amdgcn_mfma_f32_16x16x32_bf16(a0, b[nf], acc[2 * mq][nf], 0, 0, 0);
#pragma unroll
      for (int nf = 0; nf < 4; ++nf)
        acc[2 * mq + 1][nf] = __builtin_amdgcn_mfma_f32_16x16x32_bf16(a1, b[nf], acc[2 * mq + 1][nf], 0, 0, 0);
      __builtin_amdgcn_s_setprio(0);
      __builtin_amdgcn_s_barrier();
    }
  }
#undef GLOAD

  // ---- fused softmax-statistics epilogue ----
  float rowacc[8][4];
  float colacc[4];
#pragma unroll
  for (int m = 0; m < 8; ++m)
#pragma unroll
    for (int r = 0; r < 4; ++r) rowacc[m][r] = 0.f;
#pragma unroll
  for (int n = 0; n < 4; ++n) colacc[n] = 0.f;

  const float negC = -(SHIFT_C * LOG2E);
#pragma unroll
  for (int m = 0; m < 8; ++m)
#pragma unroll
    for (int n = 0; n < 4; ++n)
#pragma unroll
      for (int r = 0; r < 4; ++r) {
        float e = EXP2F(__builtin_fmaf(acc[m][n][r], LOG2E, negC));
        rowacc[m][r] += e;
        colacc[n] += e;
      }

  // diagonal logits
  if (brow == bcol && (wn >> 1) == wm) {
    float dsum = 0.f;
#pragma unroll
    for (int m = 0; m < 8; ++m)
#pragma unroll
      for (int n = 0; n < 4; ++n)
#pragma unroll
        for (int r = 0; r < 4; ++r) {
          const int rr = wm * 128 + m * 16 + lk * 4 + r;
          const int cc = wn * 64 + n * 16 + lm;
          if (rr == cc) dsum += acc[m][n][r];
        }
    dsum += __shfl_xor(dsum, 1);
    dsum += __shfl_xor(dsum, 2);
    dsum += __shfl_xor(dsum, 4);
    dsum += __shfl_xor(dsum, 8);
    dsum += __shfl_xor(dsum, 16);
    dsum += __shfl_xor(dsum, 32);
    if (lane == 0) atomicAdd(diagsum, dsum);
  }

  // row sums: C/D row=(lane>>4)*4+reg -> reduce across lane&15
#pragma unroll
  for (int m = 0; m < 8; ++m)
#pragma unroll
    for (int r = 0; r < 4; ++r) {
      float v = rowacc[m][r];
      v += __shfl_xor(v, 1);
      v += __shfl_xor(v, 2);
      v += __shfl_xor(v, 4);
      v += __shfl_xor(v, 8);
      if (lm == 0)
        atomicAdd(&rowsum[brow * BM + wm * 128 + m * 16 + lk * 4 + r], v);
    }
  // col sums: col=lane&15 -> reduce across lane>>4
#pragma unroll
  for (int n = 0; n < 4; ++n) {
    float v = colacc[n];
    v += __shfl_xor(v, 16);
    v += __shfl_xor(v, 32);
    if (lk == 0)
      atomicAdd(&colsum[bcol * BN + wn * 64 + n * 16 + lm], v);
  }
}

// ---------------- fallback (reg-staging, no ws bf16 buffers) ----------------
__global__ __launch_bounds__(256) void clip_main_fb(
    const float* __restrict__ X, const float* __restrict__ Y,
    float* __restrict__ rowsum, float* __restrict__ colsum,
    float* __restrict__ diagsum) {
  __shared__ __align__(16) unsigned char smem[2 * 128 * 64 * 2];
  unsigned char* smA = smem;
  unsigned char* smB = smem + 128 * 64 * 2;

  const int tid = threadIdx.x;
  const int bid = blockIdx.x;
  const int swz = (bid & 7) * 2048 + (bid >> 3);
  const int brow = swz >> 7;
  const int bcol = swz & 127;

  const float* xb = X + (size_t)brow * 128 * DD;
  const float* yb = Y + (size_t)bcol * 128 * DD;

  const int wid = tid >> 6, lane = tid & 63;
  const int wm = wid >> 1, wn = wid & 1;
  const int lm = lane & 15, lk = lane >> 4;

  f32x4 acc[4][4] = {};

  for (int ks = 0; ks < 4; ++ks) {
    const int kbase = ks * 64;
    if (ks) __syncthreads();
#pragma unroll
    for (int i = 0; i < 4; ++i) {
      const int c = tid + i * 256;
      const int row = c >> 3, slot = c & 7;
      const int boff = row * 128 + ((slot << 4) ^ ((row & 7) << 4));
      const float* ga = xb + row * DD + kbase + (slot << 3);
      float4 a0 = *(const float4*)ga;
      float4 a1 = *(const float4*)(ga + 4);
      uint4 pa = { pkbf(a0.x, a0.y), pkbf(a0.z, a0.w),
                   pkbf(a1.x, a1.y), pkbf(a1.z, a1.w) };
      *(uint4*)(smA + boff) = pa;
      const float* gb = yb + row * DD + kbase + (slot << 3);
      float4 b0 = *(const float4*)gb;
      float4 b1 = *(const float4*)(gb + 4);
      uint4 pb = { pkbf(b0.x, b0.y), pkbf(b0.z, b0.w),
                   pkbf(b1.x, b1.y), pkbf(b1.z, b1.w) };
      *(uint4*)(smB + boff) = pb;
    }
    __syncthreads();

#pragma unroll
    for (int kk = 0; kk < 2; ++kk) {
      const int kboff = kk * 64 + lk * 16;
      bf16x8 a[4], b[4];
#pragma unroll
      for (int m = 0; m < 4; ++m) {
        const int row = wm * 64 + m * 16 + lm;
        a[m] = *(const bf16x8*)(smA + row * 128 + (kboff ^ ((row & 7) << 4)));
      }
#pragma unroll
      for (int n = 0; n < 4; ++n) {
        const int row = wn * 64 + n * 16 + lm;
        b[n] = *(const bf16x8*)(smB + row * 128 + (kboff ^ ((row & 7) << 4)));
      }
#pragma unroll
      for (int m = 0; m < 4; ++m)
#pragma unroll
        for (int n = 0; n < 4; ++n)
          acc[m][n] = __builtin_amdgcn_mfma_f32_16x16x32_bf16(a[m], b[n], acc[m][n], 0, 0, 0);
    }
  }

  float rowacc[4][4];
  float colacc[4];
#pragma unroll
  for (int m = 0; m < 4; ++m)
#pragma unroll
    for (int r = 0; r < 4; ++r) rowacc[m][r] = 0.f;
#pragma unroll
  for (int n = 0; n < 4; ++n) colacc[n] = 0.f;

  const float negC = -(SHIFT_C * LOG2E);
#pragma unroll
  for (int m = 0; m < 4; ++m)
#pragma unroll
    for (int n = 0; n < 4; ++n)
#pragma unroll
      for (int r = 0; r < 4; ++r) {
        float e = EXP2F(__builtin_fmaf(acc[m][n][r], LOG2E, negC));
        rowacc[m][r] += e;
        colacc[n] += e;
      }

  if (brow == bcol && wm == wn) {
    float dsum = 0.f;
#pragma unroll
    for (int m = 0; m < 4; ++m)
#pragma unroll
      for (int n = 0; n < 4; ++n)
#pragma unroll
        for (int r = 0; r < 4; ++r) {
          const int rr = m * 16 + lk * 4 + r;
          const int cc = n * 16 + lm;
          if (rr == cc) dsum += acc[m][n][r];
        }
    dsum += __shfl_xor(dsum, 1);
    dsum += __shfl_xor(dsum, 2);
    dsum += __shfl_xor(dsum, 4);
    dsum += __shfl_xor(dsum, 8);
    dsum += __shfl_xor(dsum, 16);
    dsum += __shfl_xor(dsum, 32);
    if (lane == 0) atomicAdd(diagsum, dsum);
  }

#pragma unroll
  for (int m = 0; m < 4; ++m)
#pragma unroll
    for (int r = 0; r < 4; ++r) {
      float v = rowacc[m][r];
      v += __shfl_xor(v, 1);
      v += __shfl_xor(v, 2);
      v += __shfl_xor(v, 4);
      v += __shfl_xor(v, 8);
      if (lm == 0)
        atomicAdd(&rowsum[brow * 128 + wm * 64 + m * 16 + lk * 4 + r], v);
    }
#pragma unroll
  for (int n = 0; n < 4; ++n) {
    float v = colacc[n];
    v += __shfl_xor(v, 16);
    v += __shfl_xor(v, 32);
    if (lk == 0)
      atomicAdd(&colsum[bcol * 128 + wn * 64 + n * 16 + lm], v);
  }
}

__global__ __launch_bounds__(256) void clip_final(
    const float* __restrict__ rowsum, const float* __restrict__ colsum,
    const float* __restrict__ diagsum, float* __restrict__ out) {
  __shared__ double sdata[256];
  double s = 0.0;
  for (int i = threadIdx.x; i < NN; i += 256)
    s += (double)logf(rowsum[i]) + (double)logf(colsum[i]);
  sdata[threadIdx.x] = s;
  __syncthreads();
  for (int st = 128; st > 0; st >>= 1) {
    if ((int)threadIdx.x < st) sdata[threadIdx.x] += sdata[threadIdx.x + st];
    __syncthreads();
  }
  if (threadIdx.x == 0) {
    double loss = (double)SHIFT_C + sdata[0] * 0.5 / (double)NN
                - (double)diagsum[0] / (double)NN;
    out[0] = (float)loss;
  }
}

extern "C" void kernel_launch(void* const* d_in, const int* in_sizes, int n_in,
                              void* d_out, int out_size, void* d_ws, size_t ws_size,
                              hipStream_t stream) {
  const float* X = (const float*)d_in[0];
  const float* Y = (const float*)d_in[1];

  const size_t bf16_bytes = (size_t)2 * NN * DD * sizeof(unsigned short);  // 16 MB
  const size_t stats_bytes = (size_t)(2 * NN + 1) * sizeof(float);

  if (ws_size >= bf16_bytes + stats_bytes) {
    unsigned short* Xb = (unsigned short*)d_ws;
    unsigned short* Yb = Xb + (size_t)NN * DD;
    float* rowsum = (float*)((unsigned char*)d_ws + bf16_bytes);
    float* colsum = rowsum + NN;
    float* diagsum = colsum + NN;

    hipMemsetAsync(rowsum, 0, stats_bytes, stream);
    cvt_kernel<<<dim3(2 * NN * DD / 8 / 256), dim3(256), 0, stream>>>(X, Y, Xb, Yb);
    clip_gemm<<<dim3((NN / BM) * (NN / BN)), dim3(THREADS), 0, stream>>>(
        Xb, Yb, rowsum, colsum, diagsum);
    clip_final<<<dim3(1), dim3(256), 0, stream>>>(rowsum, colsum, diagsum, (float*)d_out);
  } else {
    float* rowsum = (float*)d_ws;
    float* colsum = rowsum + NN;
    float* diagsum = colsum + NN;
    hipMemsetAsync(d_ws, 0, stats_bytes, stream);
    clip_main_fb<<<dim3((NN / 128) * (NN / 128)), dim3(256), 0, stream>>>(
        X, Y, rowsum, colsum, diagsum);
    clip_final<<<dim3(1), dim3(256), 0, stream>>>(rowsum, colsum, diagsum, (float*)d_out);
  }
}

// Round 8
// 269.672 us; speedup vs baseline: 1.6340x; 1.0234x over previous
//
#include <hip/hip_runtime.h>
#include <hip/hip_bf16.h>

#define NN 16384
#define DD 256
#define BM 256
#define BN 256
#define BK 64
#define NKT 4                  // 256 / 64 K-tiles
#define THREADS 512
#define SHIFT_C 64.0f
#define LOG2E 1.4426950408889634f

typedef __attribute__((ext_vector_type(4))) float f32x4;
typedef __attribute__((ext_vector_type(8))) short bf16x8;

#if __has_builtin(__builtin_amdgcn_exp2f)
#define EXP2F(x) __builtin_amdgcn_exp2f(x)
#else
#define EXP2F(x) exp2f(x)
#endif

__device__ __forceinline__ unsigned pkbf(float a, float b) {
  float2 t; t.x = a; t.y = b;
  __hip_bfloat162 h = __float22bfloat162_rn(t);
  union { __hip_bfloat162 h; unsigned u; } cv;
  cv.h = h;
  return cv.u;
}

// sum over each 16-lane DPP row via v_add_f32 dpp row_shr; lane 15 of each
// row holds the row total. Pure VALU — no LDS-pipe traffic.
__device__ __forceinline__ float rowsum16_dpp(float v) {
  union { float f; int i; } x, t;
  x.f = v;
  t.i = __builtin_amdgcn_update_dpp(0, x.i, 0x111, 0xf, 0xf, true); x.f += t.f; // row_shr:1
  t.i = __builtin_amdgcn_update_dpp(0, x.i, 0x112, 0xf, 0xf, true); x.f += t.f; // row_shr:2
  t.i = __builtin_amdgcn_update_dpp(0, x.i, 0x114, 0xf, 0xf, true); x.f += t.f; // row_shr:4
  t.i = __builtin_amdgcn_update_dpp(0, x.i, 0x118, 0xf, 0xf, true); x.f += t.f; // row_shr:8
  return x.f;
}

// ---------------- pre-convert f32 -> bf16 ----------------
__global__ __launch_bounds__(256) void cvt_kernel(
    const float* __restrict__ X, const float* __restrict__ Y,
    unsigned short* __restrict__ Xb, unsigned short* __restrict__ Yb) {
  const int groups_per_arr = NN * DD / 8;
  int g = blockIdx.x * 256 + threadIdx.x;
  const float* src;
  unsigned short* dst;
  if (g < groups_per_arr) { src = X; dst = Xb; }
  else { src = Y; dst = Yb; g -= groups_per_arr; }
  float4 a = ((const float4*)src)[(size_t)g * 2];
  float4 b = ((const float4*)src)[(size_t)g * 2 + 1];
  uint4 p = { pkbf(a.x, a.y), pkbf(a.z, a.w), pkbf(b.x, b.y), pkbf(b.z, b.w) };
  ((uint4*)dst)[g] = p;
}

// ---------------- main fused GEMM + softmax-stats ----------------
// 256x256 tile, 8 waves (2Mx4N, wave=128x64), BK=64, 2x64KB double-buffer,
// R7's conflict-free swizzle. Schedule: software-pipelined frag reads (each
// phase reads p+1's frags, MFMAs p's) in plain C++ so the compiler emits its
// own counted lgkmcnt; ONE __syncthreads per K-tile (its vmcnt(0) drain is
// the tile-entry wait); stage for t+1 issued in phases 0-3.
__global__ __launch_bounds__(THREADS, 2) void clip_gemm(
    const unsigned short* __restrict__ Xb, const unsigned short* __restrict__ Yb,
    float* __restrict__ rowsum, float* __restrict__ colsum,
    float* __restrict__ diagsum) {
  __shared__ __align__(16) unsigned char sm[2 * 65536];  // [buf][A:32K|B:32K]

  const int tid = threadIdx.x;
  const int bid = blockIdx.x;
  // bijective 2-level XCD swizzle: 4096 blocks = 8 xcd x 8 col-panels x 64
  const int xcd = bid & 7;
  const int t0 = bid >> 3;
  const int stp = t0 >> 6;
  const int idx = t0 & 63;
  const int brow = xcd * 8 + (idx >> 3);   // 0..63
  const int bcol = stp * 8 + (idx & 7);    // 0..63

  const unsigned short* xb = Xb + (size_t)brow * BM * DD;
  const unsigned short* yb = Yb + (size_t)bcol * BN * DD;

  const int wid = tid >> 6, lane = tid & 63;
  const int wm = wid >> 2, wn = wid & 3;   // wave = rows [wm*128,+128) x cols [wn*64,+64)
  const int lm = lane & 15, lk = lane >> 4;

  // staging slots: per array 2048 x 16B ([256 rows][8 subslots]); 4/thread.
  // LDS slot (row, sl) holds source subslot g = sl ^ (row&7)  (involution).
  int sg[4], sd[4];
#pragma unroll
  for (int j = 0; j < 4; ++j) {
    const int s = j * 512 + tid;
    const int row = s >> 3;
    const int g = (s & 7) ^ (row & 7);
    sg[j] = row * DD + g * 8;
    sd[j] = s * 16;
  }

  // read-side swizzled subslot bytes for kh=0/1 (proven 0-conflict in R7)
  const int sl0 = ((lk ^ (lm & 7)) << 4);
  const int sl1 = (((4 | lk) ^ (lm & 7)) << 4);

  f32x4 acc[8][4] = {};

#define GLOAD(t1, j)                                                           \
  {                                                                            \
    __builtin_amdgcn_global_load_lds(                                          \
        (const __attribute__((address_space(1))) unsigned*)(xb + sg[j] + (t1) * BK), \
        (__attribute__((address_space(3))) unsigned*)(sm + ((t1) & 1) * 65536 + sd[j]), \
        16, 0, 0);                                                             \
    __builtin_amdgcn_global_load_lds(                                          \
        (const __attribute__((address_space(1))) unsigned*)(yb + sg[j] + (t1) * BK), \
        (__attribute__((address_space(3))) unsigned*)(sm + ((t1) & 1) * 65536 + 32768 + sd[j]), \
        16, 0, 0);                                                             \
  }

#define RDA(buf, mi, sl) (*(const bf16x8*)((buf) + (wm * 128 + (mi) * 16 + lm) * 128 + (sl)))
#define RDB(buf, nf, sl) (*(const bf16x8*)((buf) + (wn * 64 + (nf) * 16 + lm) * 128 + (sl)))

#define MFMA8(x0, x1, bs, m0)                                                  \
  {                                                                            \
    _Pragma("unroll")                                                          \
    for (int nf = 0; nf < 4; ++nf)                                             \
      acc[m0][nf] = __builtin_amdgcn_mfma_f32_16x16x32_bf16(x0, bs[nf], acc[m0][nf], 0, 0, 0); \
    _Pragma("unroll")                                                          \
    for (int nf = 0; nf < 4; ++nf)                                             \
      acc[(m0) + 1][nf] = __builtin_amdgcn_mfma_f32_16x16x32_bf16(x1, bs[nf], acc[(m0) + 1][nf], 0, 0, 0); \
  }

  // prologue: stage tile 0
  GLOAD(0, 0); GLOAD(0, 1); GLOAD(0, 2); GLOAD(0, 3);

#pragma unroll
  for (int t = 0; t < NKT; ++t) {
    __syncthreads();  // vmcnt(0)+lgkmcnt(0)+barrier: buf[t&1] staged everywhere
    const unsigned char* bA = sm + (t & 1) * 65536;
    const unsigned char* bB = bA + 32768;
    bf16x8 aC0, aC1, aN0, aN1, b0[4], b1[4];
    // initial reads for phase 0 (kh=0, m-pair 0/1) + B(kh=0)
    aC0 = RDA(bA, 0, sl0); aC1 = RDA(bA, 1, sl0);
#pragma unroll
    for (int nf = 0; nf < 4; ++nf) b0[nf] = RDB(bB, nf, sl0);
    // p0: prefetch m2/3 kh0 ; MFMA m0/1 kh0
    if (t < NKT - 1) GLOAD(t + 1, 0);
    aN0 = RDA(bA, 2, sl0); aN1 = RDA(bA, 3, sl0);
    MFMA8(aC0, aC1, b0, 0);
    // p1
    if (t < NKT - 1) GLOAD(t + 1, 1);
    aC0 = RDA(bA, 4, sl0); aC1 = RDA(bA, 5, sl0);
    MFMA8(aN0, aN1, b0, 2);
    // p2
    if (t < NKT - 1) GLOAD(t + 1, 2);
    aN0 = RDA(bA, 6, sl0); aN1 = RDA(bA, 7, sl0);
    MFMA8(aC0, aC1, b0, 4);
    // p3: prefetch kh1 (m0/1 + B)
    if (t < NKT - 1) GLOAD(t + 1, 3);
    aC0 = RDA(bA, 0, sl1); aC1 = RDA(bA, 1, sl1);
#pragma unroll
    for (int nf = 0; nf < 4; ++nf) b1[nf] = RDB(bB, nf, sl1);
    MFMA8(aN0, aN1, b0, 6);
    // p4
    aN0 = RDA(bA, 2, sl1); aN1 = RDA(bA, 3, sl1);
    MFMA8(aC0, aC1, b1, 0);
    // p5
    aC0 = RDA(bA, 4, sl1); aC1 = RDA(bA, 5, sl1);
    MFMA8(aN0, aN1, b1, 2);
    // p6
    aN0 = RDA(bA, 6, sl1); aN1 = RDA(bA, 7, sl1);
    MFMA8(aC0, aC1, b1, 4);
    // p7
    MFMA8(aN0, aN1, b1, 6);
  }
#undef GLOAD
#undef RDA
#undef RDB
#undef MFMA8

  // ---- fused softmax-statistics epilogue ----
  float rowacc[8][4];
  float colacc[4];
#pragma unroll
  for (int m = 0; m < 8; ++m)
#pragma unroll
    for (int r = 0; r < 4; ++r) rowacc[m][r] = 0.f;
#pragma unroll
  for (int n = 0; n < 4; ++n) colacc[n] = 0.f;

  const float negC = -(SHIFT_C * LOG2E);
#pragma unroll
  for (int m = 0; m < 8; ++m)
#pragma unroll
    for (int n = 0; n < 4; ++n)
#pragma unroll
      for (int r = 0; r < 4; ++r) {
        float e = EXP2F(__builtin_fmaf(acc[m][n][r], LOG2E, negC));
        rowacc[m][r] += e;
        colacc[n] += e;
      }

  // diagonal logits
  if (brow == bcol && (wn >> 1) == wm) {
    float dsum = 0.f;
#pragma unroll
    for (int m = 0; m < 8; ++m)
#pragma unroll
      for (int n = 0; n < 4; ++n)
#pragma unroll
        for (int r = 0; r < 4; ++r) {
          const int rr = wm * 128 + m * 16 + lk * 4 + r;
          const int cc = wn * 64 + n * 16 + lm;
          if (rr == cc) dsum += acc[m][n][r];
        }
    dsum += __shfl_xor(dsum, 1);
    dsum += __shfl_xor(dsum, 2);
    dsum += __shfl_xor(dsum, 4);
    dsum += __shfl_xor(dsum, 8);
    dsum += __shfl_xor(dsum, 16);
    dsum += __shfl_xor(dsum, 32);
    if (lane == 0) atomicAdd(diagsum, dsum);
  }

  // row sums: reduce across lm via DPP (VALU); lane lm==15 holds the total
#pragma unroll
  for (int m = 0; m < 8; ++m)
#pragma unroll
    for (int r = 0; r < 4; ++r) {
      float v = rowsum16_dpp(rowacc[m][r]);
      if (lm == 15)
        atomicAdd(&rowsum[brow * BM + wm * 128 + m * 16 + lk * 4 + r], v);
    }
  // col sums: reduce across lk (4 lanes) — only 8 shfl/wave, keep
#pragma unroll
  for (int n = 0; n < 4; ++n) {
    float v = colacc[n];
    v += __shfl_xor(v, 16);
    v += __shfl_xor(v, 32);
    if (lk == 0)
      atomicAdd(&colsum[bcol * BN + wn * 64 + n * 16 + lm], v);
  }
}

// ---------------- fallback (reg-staging, no ws bf16 buffers) ----------------
__global__ __launch_bounds__(256) void clip_main_fb(
    const float* __restrict__ X, const float* __restrict__ Y,
    float* __restrict__ rowsum, float* __restrict__ colsum,
    float* __restrict__ diagsum) {
  __shared__ __align__(16) unsigned char smem[2 * 128 * 64 * 2];
  unsigned char* smA = smem;
  unsigned char* smB = smem + 128 * 64 * 2;

  const int tid = threadIdx.x;
  const int bid = blockIdx.x;
  const int swz = (bid & 7) * 2048 + (bid >> 3);
  const int brow = swz >> 7;
  const int bcol = swz & 127;

  const float* xb = X + (size_t)brow * 128 * DD;
  const float* yb = Y + (size_t)bcol * 128 * DD;

  const int wid = tid >> 6, lane = tid & 63;
  const int wm = wid >> 1, wn = wid & 1;
  const int lm = lane & 15, lk = lane >> 4;

  f32x4 acc[4][4] = {};

  for (int ks = 0; ks < 4; ++ks) {
    const int kbase = ks * 64;
    if (ks) __syncthreads();
#pragma unroll
    for (int i = 0; i < 4; ++i) {
      const int c = tid + i * 256;
      const int row = c >> 3, slot = c & 7;
      const int boff = row * 128 + ((slot << 4) ^ ((row & 7) << 4));
      const float* ga = xb + row * DD + kbase + (slot << 3);
      float4 a0 = *(const float4*)ga;
      float4 a1 = *(const float4*)(ga + 4);
      uint4 pa = { pkbf(a0.x, a0.y), pkbf(a0.z, a0.w),
                   pkbf(a1.x, a1.y), pkbf(a1.z, a1.w) };
      *(uint4*)(smA + boff) = pa;
      const float* gb = yb + row * DD + kbase + (slot << 3);
      float4 b0 = *(const float4*)gb;
      float4 b1 = *(const float4*)(gb + 4);
      uint4 pb = { pkbf(b0.x, b0.y), pkbf(b0.z, b0.w),
                   pkbf(b1.x, b1.y), pkbf(b1.z, b1.w) };
      *(uint4*)(smB + boff) = pb;
    }
    __syncthreads();

#pragma unroll
    for (int kk = 0; kk < 2; ++kk) {
      const int kboff = kk * 64 + lk * 16;
      bf16x8 a[4], b[4];
#pragma unroll
      for (int m = 0; m < 4; ++m) {
        const int row = wm * 64 + m * 16 + lm;
        a[m] = *(const bf16x8*)(smA + row * 128 + (kboff ^ ((row & 7) << 4)));
      }
#pragma unroll
      for (int n = 0; n < 4; ++n) {
        const int row = wn * 64 + n * 16 + lm;
        b[n] = *(const bf16x8*)(smB + row * 128 + (kboff ^ ((row & 7) << 4)));
      }
#pragma unroll
      for (int m = 0; m < 4; ++m)
#pragma unroll
        for (int n = 0; n < 4; ++n)
          acc[m][n] = __builtin_amdgcn_mfma_f32_16x16x32_bf16(a[m], b[n], acc[m][n], 0, 0, 0);
    }
  }

  float rowacc[4][4];
  float colacc[4];
#pragma unroll
  for (int m = 0; m < 4; ++m)
#pragma unroll
    for (int r = 0; r < 4; ++r) rowacc[m][r] = 0.f;
#pragma unroll
  for (int n = 0; n < 4; ++n) colacc[n] = 0.f;

  const float negC = -(SHIFT_C * LOG2E);
#pragma unroll
  for (int m = 0; m < 4; ++m)
#pragma unroll
    for (int n = 0; n < 4; ++n)
#pragma unroll
      for (int r = 0; r < 4; ++r) {
        float e = EXP2F(__builtin_fmaf(acc[m][n][r], LOG2E, negC));
        rowacc[m][r] += e;
        colacc[n] += e;
      }

  if (brow == bcol && wm == wn) {
    float dsum = 0.f;
#pragma unroll
    for (int m = 0; m < 4; ++m)
#pragma unroll
      for (int n = 0; n < 4; ++n)
#pragma unroll
        for (int r = 0; r < 4; ++r) {
          const int rr = m * 16 + lk * 4 + r;
          const int cc = n * 16 + lm;
          if (rr == cc) dsum += acc[m][n][r];
        }
    dsum += __shfl_xor(dsum, 1);
    dsum += __shfl_xor(dsum, 2);
    dsum += __shfl_xor(dsum, 4);
    dsum += __shfl_xor(dsum, 8);
    dsum += __shfl_xor(dsum, 16);
    dsum += __shfl_xor(dsum, 32);
    if (lane == 0) atomicAdd(diagsum, dsum);
  }

#pragma unroll
  for (int m = 0; m < 4; ++m)
#pragma unroll
    for (int r = 0; r < 4; ++r) {
      float v = rowsum16_dpp(rowacc[m][r]);
      if (lm == 15)
        atomicAdd(&rowsum[brow * 128 + wm * 64 + m * 16 + lk * 4 + r], v);
    }
#pragma unroll
  for (int n = 0; n < 4; ++n) {
    float v = colacc[n];
    v += __shfl_xor(v, 16);
    v += __shfl_xor(v, 32);
    if (lk == 0)
      atomicAdd(&colsum[bcol * 128 + wn * 64 + n * 16 + lm], v);
  }
}

__global__ __launch_bounds__(256) void clip_final(
    const float* __restrict__ rowsum, const float* __restrict__ colsum,
    const float* __restrict__ diagsum, float* __restrict__ out) {
  __shared__ double sdata[256];
  double s = 0.0;
  for (int i = threadIdx.x; i < NN; i += 256)
    s += (double)logf(rowsum[i]) + (double)logf(colsum[i]);
  sdata[threadIdx.x] = s;
  __syncthreads();
  for (int st = 128; st > 0; st >>= 1) {
    if ((int)threadIdx.x < st) sdata[threadIdx.x] += sdata[threadIdx.x + st];
    __syncthreads();
  }
  if (threadIdx.x == 0) {
    double loss = (double)SHIFT_C + sdata[0] * 0.5 / (double)NN
                - (double)diagsum[0] / (double)NN;
    out[0] = (float)loss;
  }
}

extern "C" void kernel_launch(void* const* d_in, const int* in_sizes, int n_in,
                              void* d_out, int out_size, void* d_ws, size_t ws_size,
                              hipStream_t stream) {
  const float* X = (const float*)d_in[0];
  const float* Y = (const float*)d_in[1];

  const size_t bf16_bytes = (size_t)2 * NN * DD * sizeof(unsigned short);  // 16 MB
  const size_t stats_bytes = (size_t)(2 * NN + 1) * sizeof(float);

  if (ws_size >= bf16_bytes + stats_bytes) {
    unsigned short* Xb = (unsigned short*)d_ws;
    unsigned short* Yb = Xb + (size_t)NN * DD;
    float* rowsum = (float*)((unsigned char*)d_ws + bf16_bytes);
    float* colsum = rowsum + NN;
    float* diagsum = colsum + NN;

    hipMemsetAsync(rowsum, 0, stats_bytes, stream);
    cvt_kernel<<<dim3(2 * NN * DD / 8 / 256), dim3(256), 0, stream>>>(X, Y, Xb, Yb);
    clip_gemm<<<dim3((NN / BM) * (NN / BN)), dim3(THREADS), 0, stream>>>(
        Xb, Yb, rowsum, colsum, diagsum);
    clip_final<<<dim3(1), dim3(256), 0, stream>>>(rowsum, colsum, diagsum, (float*)d_out);
  } else {
    float* rowsum = (float*)d_ws;
    float* colsum = rowsum + NN;
    float* diagsum = colsum + NN;
    hipMemsetAsync(d_ws, 0, stats_bytes, stream);
    clip_main_fb<<<dim3((NN / 128) * (NN / 128)), dim3(256), 0, stream>>>(
        X, Y, rowsum, colsum, diagsum);
    clip_final<<<dim3(1), dim3(256), 0, stream>>>(rowsum, colsum, diagsum, (float*)d_out);
  }
}